// Round 13
// baseline (123.827 us; speedup 1.0000x reference)
//
#include <hip/hip_runtime.h>

#define T_STEPS 256
#define IMG 512
#define HW (IMG * IMG)
#define TW 16                  // tile width
#define TH 16                  // tile height
#define HROWS 20               // halo rows -2..17
#define RCHK 6                 // real chunks per halo row (cols -4..19)
#define RSTRIDE 7              // slot stride per halo row (gcd(7,8)=1 bank spread)
#define FRAME_SLOTS 192        // padded (3 glds x 64); 140 real
#define FRAME_DW 768
#define NBUF 12                // ring of 12 frames = 36 KiB LDS

// Zero page for dummy/OOB chunks (device global: never written, stays 0).
__device__ __align__(16) float g_zeropage[8] = {0, 0, 0, 0, 0, 0, 0, 0};

typedef const __attribute__((address_space(1))) unsigned int* gptr_t;
typedef __attribute__((address_space(3))) unsigned int* lptr_t;
typedef float vf4 __attribute__((ext_vector_type(4)));
typedef float vf2 __attribute__((ext_vector_type(2)));

// out[t] = 0.8*out[t-1] + conv(x)[t-1]; out[0]=0 — conv and LI scan commute.
// Thread = 2x2 px on a 16x16 tile: a wave's simultaneous ds_read_b128s span
// only 8 rows x ~5 chunks -> ~40 unique chunks/inst with 2-way multiplicity
// (same-address broadcast is free) vs the old layout's 64 distinct chunks =
// 1KB unique/inst. DS-pipe cost per CU-step ~halves; everything else (ring-12
// glds DMA, 4-frame batches, counted vmcnt never touching stores, nt stores)
// is the proven R7/R12 discipline.
__launch_bounds__(64)
__global__ void conv_li_kernel(const float* __restrict__ x,
                               const float* __restrict__ kern,
                               float* __restrict__ out) {
    __shared__ __align__(16) float lds[NBUF * FRAME_DW];
    const int tid = threadIdx.x;
    const int bid = blockIdx.x;
    // 1024 blocks over 8 XCDs (bijective): XCD k owns a 4-tile-row band.
    const int vbid = (bid & 7) * 128 + (bid >> 3);
    const int bx = vbid & 31;      // 32 tiles across
    const int by = vbid >> 5;      // 32 tile rows

    // 5x5 kernel -> wave-uniform (SGPR) weights.
    float kw[25];
#pragma unroll
    for (int i = 0; i < 25; ++i)
        kw[i] = __int_as_float(__builtin_amdgcn_readfirstlane(__float_as_int(kern[i])));

    // Staging: issue k stages slots k*64+tid -> halo row s/7, chunk col s%7
    // (c<6 real: cols 4c-4..4c-1; c=6 and row>=20 dummy -> zeropage).
    const float* src[3]; bool ok[3];
#pragma unroll
    for (int k = 0; k < 3; ++k) {
        int s = k * 64 + tid;
        int row = s / RSTRIDE, c = s - row * RSTRIDE;
        int gy = by * TH + row - 2;
        int gx = bx * TW + c * 4 - 4;
        ok[k] = (row < HROWS) && (c < RCHK) &&
                (gy >= 0) && (gy < IMG) && (gx >= 0) && (gx <= IMG - 4);
        src[k] = x + (size_t)(ok[k] ? gy : 0) * IMG + (ok[k] ? gx : 0);
    }

    auto GLDS = [&](int fi, int tf) {          // one frame = 3 glds issues
        float* fb = &lds[fi * FRAME_DW];
#pragma unroll
        for (int k = 0; k < 3; ++k) {
            const float* p = ok[k] ? src[k] + (size_t)tf * HW : g_zeropage;
            __builtin_amdgcn_global_load_lds((gptr_t)p, (lptr_t)(fb + k * 256), 16, 0, 0);
        }
    };
    auto BATCH = [&](int bufbase, int f0) {    // 4 frames = 12 glds
#pragma unroll
        for (int j = 0; j < 4; ++j) {
            int tf = f0 + j; if (tf > T_STEPS - 1) tf = T_STEPS - 1;
            GLDS(bufbase + j, tf);
        }
    };

    const int q = tid & 7;         // col-pair (cols 2q, 2q+1)
    const int r2 = tid >> 3;       // row-pair (rows 2r2, 2r2+1)
    const int sq = (q + 1) >> 1;   // first chunk of the 2-chunk window
    const bool evq = (q & 1) == 0; // even q: window starts at dword 2 of chunk
    const size_t obase = (size_t)(by * TH + 2 * r2) * IMG + bx * TW + 2 * q;

    vf2 st0 = {0.f, 0.f}, st1 = {0.f, 0.f};   // state rows 2r2, 2r2+1 (2 cols)

    auto STEP = [&](int fi, int t) {
        vf2 A00 = {0.f, 0.f}, A01 = {0.f, 0.f};   // out row0: col0-acc, col1-acc
        vf2 A10 = {0.f, 0.f}, A11 = {0.f, 0.f};   // out row1
        const float* F = &lds[fi * FRAME_DW];
#pragma unroll
        for (int j = 0; j < 6; ++j) {              // halo rows 2r2 + j
            const float* L = F + ((2 * r2 + j) * RSTRIDE + sq) * 4;
            vf4 c0 = *(const vf4*)(L);
            vf4 c1 = *(const vf4*)(L + 4);
            vf2 Q0 = {c0.x, c0.y}, Q1 = {c0.z, c0.w};
            vf2 Q2 = {c1.x, c1.y}, Q3 = {c1.z, c1.w};
            // window pairs P_i = (w_{2i}, w_{2i+1}), w_m = col 2q-2+m
            vf2 P0 = evq ? Q1 : Q0;
            vf2 P1 = evq ? Q2 : Q1;
            vf2 P2 = evq ? Q3 : Q2;
            if (j <= 4) {                          // k-row j -> out row 2r2
                const float k0 = kw[j * 5 + 0], k1 = kw[j * 5 + 1], k2 = kw[j * 5 + 2];
                const float k3 = kw[j * 5 + 3], k4 = kw[j * 5 + 4];
                const vf2 K01 = {k0, k1}, K23 = {k2, k3}, K40 = {k4, 0.f};
                const vf2 K0h = {0.f, k0}, K12 = {k1, k2}, K34 = {k3, k4};
                A00 = __builtin_elementwise_fma(K01, P0, A00);
                A00 = __builtin_elementwise_fma(K23, P1, A00);
                A00 = __builtin_elementwise_fma(K40, P2, A00);
                A01 = __builtin_elementwise_fma(K0h, P0, A01);
                A01 = __builtin_elementwise_fma(K12, P1, A01);
                A01 = __builtin_elementwise_fma(K34, P2, A01);
            }
            if (j >= 1) {                          // k-row j-1 -> out row 2r2+1
                const int m = j - 1;
                const float k0 = kw[m * 5 + 0], k1 = kw[m * 5 + 1], k2 = kw[m * 5 + 2];
                const float k3 = kw[m * 5 + 3], k4 = kw[m * 5 + 4];
                const vf2 K01 = {k0, k1}, K23 = {k2, k3}, K40 = {k4, 0.f};
                const vf2 K0h = {0.f, k0}, K12 = {k1, k2}, K34 = {k3, k4};
                A10 = __builtin_elementwise_fma(K01, P0, A10);
                A10 = __builtin_elementwise_fma(K23, P1, A10);
                A10 = __builtin_elementwise_fma(K40, P2, A10);
                A11 = __builtin_elementwise_fma(K0h, P0, A11);
                A11 = __builtin_elementwise_fma(K12, P1, A11);
                A11 = __builtin_elementwise_fma(K34, P2, A11);
            }
        }
        float* op = out + (size_t)t * HW + obase;
        __builtin_nontemporal_store(st0, (vf2*)op);          // out row 2r2
        __builtin_nontemporal_store(st1, (vf2*)(op + IMG));  // out row 2r2+1
        vf2 acc0 = {A00.x + A00.y, A01.x + A01.y};
        vf2 acc1 = {A10.x + A10.y, A11.x + A11.y};
        const vf2 m02 = {-0.2f, -0.2f};
        st0 = __builtin_elementwise_fma(m02, st0, st0) + acc0;  // 0.8*S + y
        st1 = __builtin_elementwise_fma(m02, st1, st1) + acc1;
    };

    // Prologue: B0 (frames 0-3 -> bufs 0-3), B1 (4-7 -> bufs 4-7).
    BATCH(0, 0);
    BATCH(4, 4);

    // g0: outstanding 24, need oldest 12 -> vmcnt(12).
    asm volatile("s_waitcnt vmcnt(12)" ::: "memory");
    STEP(0, 0); STEP(1, 1); STEP(2, 2); STEP(3, 3);
    BATCH(8, 8);

    // Steady (g>=1): queue old->new = B_g(12), stores(8), B_{g+1}(12) ->
    // vmcnt(20) drains exactly B_g, never waits on stores.
#pragma clang loop unroll(disable)
    for (int sg = 0; sg < 21; ++sg) {
        const int t0 = 4 + sg * 12;
        asm volatile("s_waitcnt vmcnt(20)" ::: "memory");
        STEP(4, t0 + 0); STEP(5, t0 + 1); STEP(6, t0 + 2); STEP(7, t0 + 3);
        BATCH(0, t0 + 8);
        asm volatile("s_waitcnt vmcnt(20)" ::: "memory");
        STEP(8, t0 + 4); STEP(9, t0 + 5); STEP(10, t0 + 6); STEP(11, t0 + 7);
        BATCH(4, t0 + 12);
        asm volatile("s_waitcnt vmcnt(20)" ::: "memory");
        STEP(0, t0 + 8); STEP(1, t0 + 9); STEP(2, t0 + 10); STEP(3, t0 + 11);
        BATCH(8, t0 + 16);
    }
}

extern "C" void kernel_launch(void* const* d_in, const int* in_sizes, int n_in,
                              void* d_out, int out_size, void* d_ws, size_t ws_size,
                              hipStream_t stream) {
    const float* x = (const float*)d_in[0];      // [256,1,512,512] f32
    const float* kern = (const float*)d_in[1];   // [5,5] f32
    float* out = (float*)d_out;                  // [256,1,512,512] f32

    conv_li_kernel<<<dim3(1024), dim3(64), 0, stream>>>(x, kern, out);
}